// Round 3
// baseline (196.518 us; speedup 1.0000x reference)
//
#include <hip/hip_runtime.h>

// Q6ArithmeticLayer: out = softmax(-hs * 3*(1 - dot(normalize(tanh(x@W^T)), normalize(P))))
// x: (32768, 1024) fp32 -> 134 MB stream; HBM floor ~21 us @ 6.3 TB/s.
// R3: persistent streaming. 512 blocks x 256 thr = 2048 waves = exactly 2
// resident blocks/CU (one generation, no drain/refill). Each wave owns 16
// contiguous tokens (32 KB), TPI=2, 8 iterations, double-buffered prefetch:
// next iteration's 8 dwordx4 issue before the current reduce/epilogue, so the
// CU always has ~64 KB of reads in flight (~9 KB needed for full HBM rate).
// W (6x16 cols = 96 VGPRs/lane) loaded once per wave, amortized over 16 tokens.

#define DIM 1024
#define NK 6
#define NPROTO 8
#define TPI 2
#define ITERS 8

__global__ __launch_bounds__(256, 2) void q6_fused_kernel(
    const float* __restrict__ x,
    const float* __restrict__ W,
    const float* __restrict__ protos,
    const float* __restrict__ hs_ptr,
    float* __restrict__ out,
    int n_tokens)
{
    const int lane = threadIdx.x & 63;
    const int wave_id = blockIdx.x * (blockDim.x >> 6) + (threadIdx.x >> 6);
    const int cbase = lane * 4;  // this lane's base column within each 256-col group

    // --- W fragment in registers: 6 rows x 4 x float4 = 96 VGPRs ---
    float4 wreg[NK][4];
#pragma unroll
    for (int k = 0; k < NK; ++k)
#pragma unroll
        for (int j = 0; j < 4; ++j)
            wreg[k][j] = *reinterpret_cast<const float4*>(&W[k * DIM + j * 256 + cbase]);

    // --- normalized prototype for this lane's proto slot ---
    const int pl = lane & 7;
    float p[NK];
#pragma unroll
    for (int k = 0; k < NK; ++k) p[k] = protos[pl * NK + k];
    {
        float pn = sqrtf(p[0]*p[0] + p[1]*p[1] + p[2]*p[2] + p[3]*p[3] + p[4]*p[4] + p[5]*p[5]);
        float inv = 1.0f / fmaxf(pn, 1e-12f);
#pragma unroll
        for (int k = 0; k < NK; ++k) p[k] *= inv;
    }
    const float hs = hs_ptr[0];

    const bool hi5 = (lane & 32) != 0;
    const int tloc = lane >> 5;   // which of the 2 tokens this 32-lane half owns
    const int pidx = lane & 31;   // proto slot within the half (active if <8)

    const int tok0 = wave_id * (TPI * ITERS);  // 16 contiguous tokens per wave
    if (tok0 >= n_tokens) return;

    // --- double-buffered x tiles: 2 bufs x 2 tokens x 4 float4 = 64 VGPRs ---
    float4 xbuf[2][TPI][4];
#pragma unroll
    for (int t = 0; t < TPI; ++t) {
        const float* xt = x + (size_t)(tok0 + t) * DIM;
#pragma unroll
        for (int j = 0; j < 4; ++j)
            xbuf[0][t][j] = *reinterpret_cast<const float4*>(&xt[j * 256 + cbase]);
    }

#pragma unroll 2
    for (int i = 0; i < ITERS; ++i) {
        const int cur = i & 1;
        const int tb = tok0 + i * TPI;

        // ---- prefetch next iteration's tokens (clamped, wave-uniform) ----
        int nb = tb + TPI;
        if (nb > n_tokens - TPI) nb = n_tokens - TPI;
#pragma unroll
        for (int t = 0; t < TPI; ++t) {
            const float* xt = x + (size_t)(nb + t) * DIM;
#pragma unroll
            for (int j = 0; j < 4; ++j)
                xbuf[cur ^ 1][t][j] = *reinterpret_cast<const float4*>(&xt[j * 256 + cbase]);
        }

        // ---- partial dots: acc[t][k] over this lane's 16 cols ----
        float acc[TPI][NK];
#pragma unroll
        for (int t = 0; t < TPI; ++t)
#pragma unroll
            for (int k = 0; k < NK; ++k) acc[t][k] = 0.0f;
#pragma unroll
        for (int t = 0; t < TPI; ++t)
#pragma unroll
            for (int j = 0; j < 4; ++j) {
                const float4 xvj = xbuf[cur][t][j];
#pragma unroll
                for (int k = 0; k < NK; ++k) {
                    float a = acc[t][k];
                    a = fmaf(xvj.x, wreg[k][j].x, a);
                    a = fmaf(xvj.y, wreg[k][j].y, a);
                    a = fmaf(xvj.z, wreg[k][j].z, a);
                    a = fmaf(xvj.w, wreg[k][j].w, a);
                    acc[t][k] = a;
                }
            }

        // ---- xor32 token reduce-scatter (6 shfl): half-wave h owns token h ----
        float z[NK];
#pragma unroll
        for (int k = 0; k < NK; ++k) {
            float send = hi5 ? acc[0][k] : acc[1][k];
            float keep = hi5 ? acc[1][k] : acc[0][k];
            z[k] = keep + __shfl_xor(send, 32, 64);
        }
        // ---- butterfly within the 32-lane half (30 shfl) ----
#pragma unroll
        for (int off = 16; off >= 1; off >>= 1)
#pragma unroll
            for (int k = 0; k < NK; ++k)
                z[k] += __shfl_xor(z[k], off, 64);

        // ---- epilogue: lanes p<8 of each half handle proto p of token tloc ----
        if (pidx < NPROTO) {
            float zz[NK];
            float nrm2 = 0.0f;
#pragma unroll
            for (int k = 0; k < NK; ++k) {
                float a = z[k];
                // tanh(a) = sign(a)*(1-e)/(1+e), e = exp(-2|a|) — hw v_exp_f32
                float e = __expf(-2.0f * fabsf(a));
                float th = (1.0f - e) / (1.0f + e);
                zz[k] = copysignf(th, a);
                nrm2 = fmaf(zz[k], zz[k], nrm2);
            }
            float inv = 1.0f / fmaxf(sqrtf(nrm2), 1e-6f);
            float dot = (zz[0]*p[0] + zz[1]*p[1] + zz[2]*p[2] +
                         zz[3]*p[3] + zz[4]*p[4] + zz[5]*p[5]) * inv;
            float logit = -hs * (6.0f - dot * 6.0f) * 0.5f;
            float m = logit;
            m = fmaxf(m, __shfl_xor(m, 1, 64));
            m = fmaxf(m, __shfl_xor(m, 2, 64));
            m = fmaxf(m, __shfl_xor(m, 4, 64));
            float e = __expf(logit - m);
            float s = e;
            s += __shfl_xor(s, 1, 64);
            s += __shfl_xor(s, 2, 64);
            s += __shfl_xor(s, 4, 64);
            out[(size_t)(tb + tloc) * NPROTO + pidx] = e / s;
        }
    }
}

extern "C" void kernel_launch(void* const* d_in, const int* in_sizes, int n_in,
                              void* d_out, int out_size, void* d_ws, size_t ws_size,
                              hipStream_t stream) {
    const float* x      = (const float*)d_in[0];
    const float* W      = (const float*)d_in[1];
    const float* protos = (const float*)d_in[2];
    const float* hs     = (const float*)d_in[3];
    float* out = (float*)d_out;

    const int n_tokens = in_sizes[0] / DIM;   // 32768
    const int blocks = 512;                   // 2048 waves x 16 tokens = 32768
    const int threads = 256;                  // exactly 2 resident blocks/CU

    q6_fused_kernel<<<blocks, threads, 0, stream>>>(
        x, W, protos, hs, out, n_tokens);
}